// Round 3
// baseline (1504.762 us; speedup 1.0000x reference)
//
#include <hip/hip_runtime.h>
#include <math.h>

constexpr int cB = 128, cS = 256, cF = 10, cE = 40, cNH = 8, cDH = 5;
constexpr int cI = 128, cMDH = 16, cK = 4;

__device__ __forceinline__ float lane_bcast(float v, int l) {
    return __uint_as_float(__builtin_amdgcn_readlane(__float_as_uint(v), l));
}

// ---------------- h = x @ in_w.T + in_b + pos_encoding ----------------
__global__ __launch_bounds__(256) void init_k(const float* __restrict__ x, const float* __restrict__ w,
                                              const float* __restrict__ b, float* __restrict__ h) {
    int idx = blockIdx.x * 256 + threadIdx.x;     // B*S*E
    int e = idx % cE; int bs = idx / cE; int s = bs % cS;
    float acc = b[e];
    const float* xr = x + (size_t)bs * cF;
#pragma unroll
    for (int f = 0; f < cF; ++f) acc += xr[f] * w[e * cF + f];
    int i2 = e >> 1;
    float div = expf(-(float)(2 * i2) * (logf(10000.f) / 40.0f));
    float arg = (float)s * div;
    acc += (e & 1) ? cosf(arg) : sinf(arg);
    h[idx] = acc;
}

// ---------------- fused LayerNorm + up-projection (E=40 -> 256) ----------------
__global__ __launch_bounds__(256) void ln_up_k(const float* __restrict__ h, const float* __restrict__ lnw,
                                               const float* __restrict__ upw, float* __restrict__ xmz) {
    __shared__ float lnr[8][cE];
    int row0 = blockIdx.x * 8;
    int tid = threadIdx.x;
    if (tid < 8) {
        const float* r = h + (size_t)(row0 + tid) * cE;
        float mu = 0.f;
        for (int k = 0; k < cE; ++k) mu += r[k];
        mu *= (1.f / cE);
        float va = 0.f;
        for (int k = 0; k < cE; ++k) { float d = r[k] - mu; va += d * d; }
        va *= (1.f / cE);
        float rs = rsqrtf(va + 1e-5f);
        for (int k = 0; k < cE; ++k) lnr[tid][k] = (r[k] - mu) * rs * lnw[k];
    }
    __syncthreads();
    int o = tid;   // 0..255
    float acc[8] = {0, 0, 0, 0, 0, 0, 0, 0};
    for (int k = 0; k < cE; ++k) {
        float wv = upw[o * cE + k];
#pragma unroll
        for (int r = 0; r < 8; ++r) acc[r] += lnr[r][k] * wv;
    }
#pragma unroll
    for (int r = 0; r < 8; ++r) xmz[(size_t)(row0 + r) * 256 + o] = acc[r];
}

// ---------------- depthwise causal conv (K=4) + SiLU ----------------
template <int C>
__global__ __launch_bounds__(256) void conv_silu_k(const float* __restrict__ in, int instride,
                                                   const float* __restrict__ w, const float* __restrict__ bias,
                                                   float* __restrict__ out) {
    int idx = blockIdx.x * 256 + threadIdx.x;   // B*S*C
    int c = idx % C; int bs = idx / C; int s = bs % cS;
    float acc = bias[c];
#pragma unroll
    for (int j = 0; j < cK; ++j) {
        int sj = s - 3 + j;
        if (sj >= 0) acc += in[(size_t)(bs + j - 3) * instride + c] * w[c * cK + j];
    }
    float sg = 1.f / (1.f + __expf(-acc));
    out[idx] = acc * sg;
}

// ---------------- block-diagonal headwise q,k,v ----------------
__global__ __launch_bounds__(256) void qkv_k(const float* __restrict__ xc, const float* __restrict__ xmz,
                                             const float* __restrict__ qw, const float* __restrict__ kw,
                                             const float* __restrict__ vw,
                                             float* __restrict__ qb, float* __restrict__ kb, float* __restrict__ vb) {
    int idx = blockIdx.x * 256 + threadIdx.x;   // B*S*I
    int c = idx & 127; int bs = idx >> 7;
    int n = c >> 2, o = c & 3;
    const float* xcr = xc + (size_t)bs * cI + n * 4;
    const float* xmr = xmz + (size_t)bs * 256 + n * 4;
    const float* qwp = qw + n * 16 + o * 4;
    const float* kwp = kw + n * 16 + o * 4;
    const float* vwp = vw + n * 16 + o * 4;
    float aq = 0, ak = 0, av = 0;
#pragma unroll
    for (int i = 0; i < 4; ++i) { float a = xcr[i], m = xmr[i]; aq += a * qwp[i]; ak += a * kwp[i]; av += m * vwp[i]; }
    qb[idx] = aq; kb[idx] = ak; vb[idx] = av;
}

// ---------------- input/forget gate pre-activations ip, fp (B,NH,S) ----------------
__global__ __launch_bounds__(256) void gates_k(const float* __restrict__ qb, const float* __restrict__ kb,
                                               const float* __restrict__ vb, const float* __restrict__ igw,
                                               const float* __restrict__ igb, const float* __restrict__ fgw,
                                               const float* __restrict__ fgb,
                                               float* __restrict__ ipb, float* __restrict__ fpb) {
    __shared__ float g[16 * 388];   // padded stride (384%32==0 would be 16-way conflict)
    int row0 = blockIdx.x * 16;
    for (int i = threadIdx.x; i < 16 * 384; i += 256) {
        int r = i / 384, c = i % 384;
        size_t gr = (size_t)(row0 + r) * cI;
        float v;
        if (c < 128) v = qb[gr + c];
        else if (c < 256) v = kb[gr + c - 128];
        else v = vb[gr + c - 256];
        g[r * 388 + c] = v;
    }
    __syncthreads();
    int r = threadIdx.x >> 4; int ho = threadIdx.x & 15;
    int h = ho & 7; int wch = ho >> 3;
    const float* W = (wch ? fgw : igw) + h * 384;
    const float* gr2 = g + r * 388;
    float acc = 0.f;
    for (int c = 0; c < 384; ++c) acc += gr2[c] * W[c];
    acc += wch ? fgb[h] : igb[h];
    int grow = row0 + r; int b = grow >> 8; int s = grow & 255;
    float* dst = wch ? fpb : ipb;
    dst[(size_t)(b * cNH + h) * cS + s] = acc;
}

// ---------------- fused mLSTM attention: gate scans + causal qk*D*v ----------------
// 1 wave per (b,h); 4 rows/thread; K/V broadcast from LDS, amortized over 4 rows.
__global__ __launch_bounds__(64) void attn_k(const float* __restrict__ qg, const float* __restrict__ kg,
                                             const float* __restrict__ vg, const float* __restrict__ ipg,
                                             const float* __restrict__ fpg, float* __restrict__ hatt) {
    int bh = blockIdx.x; int b = bh >> 3, h = bh & 7;
    int lane = threadIdx.x;
    __shared__ float sA[cS], sMx[cS], sFc[cS];
    __shared__ float sKf[cS * cMDH], sVf[cS * cMDH];

    // --- Fc = cumsum(log_sigmoid(fp)); a[t]=ip[t]-Fc[t]; Mx = prefix-max(a) ---
    const float4 fp4 = ((const float4*)(fpg + (size_t)bh * cS))[lane];
    const float4 ip4 = ((const float4*)(ipg + (size_t)bh * cS))[lane];
    float fpa[4] = {fp4.x, fp4.y, fp4.z, fp4.w};
    float ipa[4] = {ip4.x, ip4.y, ip4.z, ip4.w};
    float p[4];
    {
        float run = 0.f;
#pragma unroll
        for (int i = 0; i < 4; ++i) {
            float xx = fpa[i];
            float lsg = fminf(xx, 0.f) - log1pf(expf(-fabsf(xx)));
            run += lsg; p[i] = run;
        }
    }
    float cum = p[3];
#pragma unroll
    for (int off = 1; off < 64; off <<= 1) { float t = __shfl_up(cum, off); if (lane >= off) cum += t; }
    float excl = cum - p[3];
    float aa[4];
#pragma unroll
    for (int i = 0; i < 4; ++i) {
        float fcv = excl + p[i];
        aa[i] = ipa[i] - fcv;
        sFc[lane * 4 + i] = fcv;
        sA[lane * 4 + i] = aa[i];
    }
    float mq[4]; mq[0] = aa[0];
#pragma unroll
    for (int i = 1; i < 4; ++i) mq[i] = fmaxf(mq[i - 1], aa[i]);
    float cm = mq[3];
#pragma unroll
    for (int off = 1; off < 64; off <<= 1) { float t = __shfl_up(cm, off); if (lane >= off) cm = fmaxf(cm, t); }
    float exm = __shfl_up(cm, 1);
    if (lane == 0) exm = -3.0e38f;
#pragma unroll
    for (int i = 0; i < 4; ++i) sMx[lane * 4 + i] = fmaxf(exm, mq[i]);

    // --- stage K,V to LDS; q to registers ---
    float qreg[4][16];
#pragma unroll
    for (int r = 0; r < 4; ++r) {
        int t = lane + 64 * r;
        const float4* kp = (const float4*)(kg + ((size_t)(b * cS) + t) * cI + h * cMDH);
        const float4* vp = (const float4*)(vg + ((size_t)(b * cS) + t) * cI + h * cMDH);
        float4* kd = (float4*)(sKf + t * cMDH);
        float4* vd = (float4*)(sVf + t * cMDH);
#pragma unroll
        for (int j = 0; j < 4; ++j) { kd[j] = kp[j]; vd[j] = vp[j]; }
        const float4* qp = (const float4*)(qg + ((size_t)(b * cS) + t) * cI + h * cMDH);
#pragma unroll
        for (int j = 0; j < 4; ++j) {
            float4 t4 = qp[j];
            qreg[r][4 * j] = t4.x; qreg[r][4 * j + 1] = t4.y; qreg[r][4 * j + 2] = t4.z; qreg[r][4 * j + 3] = t4.w;
        }
    }
    __syncthreads();

    float MxR[4], flr[4];
#pragma unroll
    for (int r = 0; r < 4; ++r) { int s = lane + 64 * r; MxR[r] = sMx[s]; flr[r] = expf(-(sFc[s] + sMx[s])); }
    float acc[4][16];
#pragma unroll
    for (int r = 0; r < 4; ++r)
#pragma unroll
        for (int d = 0; d < 16; ++d) acc[r][d] = 0.f;
    float sumC[4] = {0, 0, 0, 0};

    for (int t = 0; t < cS; ++t) {
        float at = sA[t];
        float kv[16], vv[16];
#pragma unroll
        for (int j = 0; j < 4; ++j) {
            float4 t4 = ((const float4*)(sKf + t * cMDH))[j];
            kv[4 * j] = t4.x; kv[4 * j + 1] = t4.y; kv[4 * j + 2] = t4.z; kv[4 * j + 3] = t4.w;
            float4 u4 = ((const float4*)(sVf + t * cMDH))[j];
            vv[4 * j] = u4.x; vv[4 * j + 1] = u4.y; vv[4 * j + 2] = u4.z; vv[4 * j + 3] = u4.w;
        }
#pragma unroll
        for (int r = 0; r < 4; ++r) {
            if (t <= 63 + 64 * r) {               // uniform: whole wave skips dead chunks
                if (t <= lane + 64 * r) {         // per-lane causal mask
                    float wgt = __expf(at - MxR[r]);   // a[t]-Mx[s] <= 0
                    float qk = 0.f;
#pragma unroll
                    for (int d = 0; d < 16; ++d) qk += qreg[r][d] * kv[d];
                    float ccf = qk * 0.25f * wgt;
                    sumC[r] += ccf;
#pragma unroll
                    for (int d = 0; d < 16; ++d) acc[r][d] += ccf * vv[d];
                }
            }
        }
    }
#pragma unroll
    for (int r = 0; r < 4; ++r) {
        int s = lane + 64 * r;
        float nrm = fmaxf(fabsf(sumC[r]), flr[r]) + 1e-6f;
        float inv = 1.f / nrm;
        float4* op = (float4*)(hatt + ((size_t)(b * cS) + s) * cI + h * cMDH);
#pragma unroll
        for (int j = 0; j < 4; ++j)
            op[j] = make_float4(acc[r][4 * j] * inv, acc[r][4 * j + 1] * inv,
                                acc[r][4 * j + 2] * inv, acc[r][4 * j + 3] * inv);
    }
}

// ---------------- multihead-norm + skip*x_c, gated by silu(z); in-place on hatt ----------------
__global__ __launch_bounds__(256) void mhn_y_k(float* __restrict__ hatt, const float* __restrict__ xc,
                                               const float* __restrict__ xmz, const float* __restrict__ mhnw,
                                               const float* __restrict__ skip) {
    int idx = blockIdx.x * 256 + threadIdx.x;   // B*S*NH
    int h = idx & 7; int row = idx >> 3;
    float* hp = hatt + (size_t)row * cI + h * cMDH;
    float xv[16];
#pragma unroll
    for (int d = 0; d < 16; ++d) xv[d] = hp[d];
    float mu = 0;
#pragma unroll
    for (int d = 0; d < 16; ++d) mu += xv[d];
    mu *= (1.f / 16);
    float va = 0;
#pragma unroll
    for (int d = 0; d < 16; ++d) { float dd = xv[d] - mu; va += dd * dd; }
    va *= (1.f / 16);
    float rs = rsqrtf(va + 1e-5f);
#pragma unroll
    for (int d = 0; d < 16; ++d) {
        int i = h * cMDH + d;
        float z = xmz[(size_t)row * 256 + 128 + i];
        float sg = 1.f / (1.f + __expf(-z));
        hp[d] = ((xv[d] - mu) * rs * mhnw[i] + skip[i] * xc[(size_t)row * cI + i]) * (z * sg);
    }
}

// ---------------- down-projection (128 -> 40) + residual into h ----------------
__global__ __launch_bounds__(320) void down_res_k(const float* __restrict__ y, const float* __restrict__ dw,
                                                  float* __restrict__ h) {
    __shared__ float yl[8 * 128];
    int row0 = blockIdx.x * 8;
    for (int i = threadIdx.x; i < 1024; i += 320) yl[i] = y[(size_t)row0 * cI + i];
    __syncthreads();
    int r = threadIdx.x / 40, e = threadIdx.x % 40;
    const float* dr = dw + e * cI;
    const float* yr = yl + r * cI;
    float acc = 0.f;
    for (int i = 0; i < cI; ++i) acc += yr[i] * dr[i];
    h[(size_t)(row0 + r) * cE + e] += acc;
}

// ---------------- plain row LayerNorm (E=40) ----------------
__global__ __launch_bounds__(256) void ln_rows_k(const float* __restrict__ h, const float* __restrict__ w,
                                                 float* __restrict__ out) {
    int rid = blockIdx.x * 256 + threadIdx.x;
    const float* r = h + (size_t)rid * cE;
    float mu = 0;
    for (int k = 0; k < cE; ++k) mu += r[k];
    mu *= (1.f / cE);
    float va = 0;
    for (int k = 0; k < cE; ++k) { float d = r[k] - mu; va += d * d; }
    va *= (1.f / cE);
    float rs = rsqrtf(va + 1e-5f);
    float* o = out + (size_t)rid * cE;
    for (int k = 0; k < cE; ++k) o[k] = (r[k] - mu) * rs * w[k];
}

// ---------------- sLSTM gate pre-activations ----------------
// gall layout [blk=bh/16][s][w=bh%16][e][g]: each scan block streams a fully
// contiguous 1280 B chunk per step. Linear idx == write address (coalesced).
__global__ __launch_bounds__(256) void sgates_k(const float* __restrict__ xcs, const float* __restrict__ ln1,
                                                const float* __restrict__ wi, const float* __restrict__ wf,
                                                const float* __restrict__ wz, const float* __restrict__ wo,
                                                float* __restrict__ gall) {
    int idx = blockIdx.x * 256 + threadIdx.x;   // 256*1024*20
    int g = idx & 3; int r1 = idx >> 2;
    int e = r1 % 5; int r2 = r1 / 5;
    int w16 = r2 & 15; int r3 = r2 >> 4;
    int s = r3 & 255; int blk = r3 >> 8;
    int bh = blk * 16 + w16;
    int b = bh >> 3, h = bh & 7;
    const float* in = (g < 2) ? xcs : ln1;
    const float* w = (g == 0) ? wi : (g == 1) ? wf : (g == 2) ? wz : wo;
    const float* ir = in + ((size_t)(b * cS) + s) * cE + h * cDH;
    const float* wp = w + h * 25 + e * 5;
    float acc = 0.f;
#pragma unroll
    for (int i = 0; i < 5; ++i) acc += ir[i] * wp[i];
    gall[idx] = acc;
}

// ---------------- sLSTM sequential scan ----------------
// 16 waves/block (4 waves/SIMD -> latency hiding across independent chains),
// 1 chain per wave on lanes 0..4; R column in registers; depth-8 register-ring
// prefetch of gall (contiguous per block) and h_old; mhn fused; h written
// directly per step (no LDS, no syncthreads).
__global__ __launch_bounds__(1024) void scan_k(const float* __restrict__ gall, const float* __restrict__ R,
                                               const float* __restrict__ bias, const float* __restrict__ mhnw,
                                               float* __restrict__ hbuf) {
    int wv = threadIdx.x >> 6;
    int lane = threadIdx.x & 63;
    if (lane >= cDH) return;
    int bh = blockIdx.x * 16 + wv;      // 64 blocks * 16 waves = 1024 chains
    int b = bh >> 3, h = bh & 7;
    int e = lane;

    float Rr[4][5];                     // R[h][g][d][e]
#pragma unroll
    for (int g = 0; g < 4; ++g)
#pragma unroll
        for (int d = 0; d < 5; ++d) Rr[g][d] = R[h * 100 + g * 25 + d * 5 + e];
    float bg[4];
#pragma unroll
    for (int g = 0; g < 4; ++g) bg[g] = bias[h * 20 + g * 5 + e];
    float wmh = mhnw[h * 5 + e];

    // gall float4 index: ((blk*256 + t)*16 + wv)*5 + e ; step stride = 80 float4s
    const float4* gp = (const float4*)gall + (((size_t)blockIdx.x * 256) * 16 + wv) * 5 + e;
    float* hb = hbuf + (size_t)b * cS * cE + h * cDH + e;   // + t*40

    float4 rg[8];
    float rh[8];
#pragma unroll
    for (int j = 0; j < 8; ++j) { rg[j] = gp[(size_t)j * 80]; rh[j] = hb[(size_t)j * 40]; }

    float cstate = 0.f, nstate = 0.f, mstate = 0.f;
    float hs0 = 0.f, hs1 = 0.f, hs2 = 0.f, hs3 = 0.f, hs4 = 0.f;

    for (int t = 0; t < cS; t += 8) {
#pragma unroll
        for (int j = 0; j < 8; ++j) {
            float4 g4 = rg[j];
            float hold = rh[j];
            int tp = t + j + 8;          // prefetch 8 ahead (pads overread into ws: harmless, unused)
            rg[j] = gp[(size_t)tp * 80];
            rh[j] = hb[(size_t)tp * 40];

            float ir = g4.x + bg[0], fr = g4.y + bg[1], zr = g4.z + bg[2], orr = g4.w + bg[3];
            ir = fmaf(hs0, Rr[0][0], ir); fr = fmaf(hs0, Rr[1][0], fr);
            zr = fmaf(hs0, Rr[2][0], zr); orr = fmaf(hs0, Rr[3][0], orr);
            ir = fmaf(hs1, Rr[0][1], ir); fr = fmaf(hs1, Rr[1][1], fr);
            zr = fmaf(hs1, Rr[2][1], zr); orr = fmaf(hs1, Rr[3][1], orr);
            ir = fmaf(hs2, Rr[0][2], ir); fr = fmaf(hs2, Rr[1][2], fr);
            zr = fmaf(hs2, Rr[2][2], zr); orr = fmaf(hs2, Rr[3][2], orr);
            ir = fmaf(hs3, Rr[0][3], ir); fr = fmaf(hs3, Rr[1][3], fr);
            zr = fmaf(hs3, Rr[2][3], zr); orr = fmaf(hs3, Rr[3][3], orr);
            ir = fmaf(hs4, Rr[0][4], ir); fr = fmaf(hs4, Rr[1][4], fr);
            zr = fmaf(hs4, Rr[2][4], zr); orr = fmaf(hs4, Rr[3][4], orr);

            float lsg = fminf(fr, 0.f) - __logf(1.f + __expf(-fabsf(fr)));
            float lfm = mstate + lsg;
            float mn = fmaxf(ir, lfm);
            float ig = __expf(ir - mn), fg = __expf(lfm - mn);
            float th = 1.f - 2.f * __builtin_amdgcn_rcpf(__expf(2.f * zr) + 1.f);
            float cn = fg * cstate + ig * th;
            float nn = fg * nstate + ig;
            float sg = __builtin_amdgcn_rcpf(1.f + __expf(-orr));
            float hn = sg * cn * __builtin_amdgcn_rcpf(nn);
            cstate = cn; nstate = nn; mstate = mn;

            hs0 = lane_bcast(hn, 0); hs1 = lane_bcast(hn, 1); hs2 = lane_bcast(hn, 2);
            hs3 = lane_bcast(hn, 3); hs4 = lane_bcast(hn, 4);
            float mu = ((hs0 + hs1) + (hs2 + hs3) + hs4) * 0.2f;
            float d0 = hs0 - mu, d1 = hs1 - mu, d2 = hs2 - mu, d3 = hs3 - mu, d4 = hs4 - mu;
            float va = (d0 * d0 + d1 * d1 + d2 * d2 + d3 * d3 + d4 * d4) * 0.2f;
            float rs = __builtin_amdgcn_rsqf(va + 1e-5f);
            hb[(size_t)(t + j) * 40] = hold + (hn - mu) * rs * wmh;
        }
    }
}

// ---------------- FFN: fused LN + up-proj + exact GELU gate ----------------
__global__ __launch_bounds__(256) void ff1_k(const float* __restrict__ h, const float* __restrict__ lnw,
                                             const float* __restrict__ upw, float* __restrict__ ff) {
    __shared__ float lnr[4][cE];
    int row0 = blockIdx.x * 4;
    int tid = threadIdx.x;
    if (tid < 4) {
        const float* r = h + (size_t)(row0 + tid) * cE;
        float mu = 0;
        for (int k = 0; k < cE; ++k) mu += r[k];
        mu *= (1.f / cE);
        float va = 0;
        for (int k = 0; k < cE; ++k) { float d = r[k] - mu; va += d * d; }
        va *= (1.f / cE);
        float rs = rsqrtf(va + 1e-5f);
        for (int k = 0; k < cE; ++k) lnr[tid][k] = (r[k] - mu) * rs * lnw[k];
    }
    __syncthreads();
    int r = tid >> 6, f = tid & 63;
    float a = 0, u = 0;
    for (int k = 0; k < cE; ++k) {
        float xv = lnr[r][k];
        a += xv * upw[f * cE + k];
        u += xv * upw[(64 + f) * cE + k];
    }
    float g = 0.5f * a * (1.f + erff(a * 0.70710678118f));
    ff[(size_t)(row0 + r) * 64 + f] = g * u;
}

__global__ __launch_bounds__(320) void ff2_k(const float* __restrict__ ff, const float* __restrict__ dw,
                                             float* __restrict__ h) {
    __shared__ float fl[8 * 64];
    int row0 = blockIdx.x * 8;
    for (int i = threadIdx.x; i < 512; i += 320) fl[i] = ff[(size_t)row0 * 64 + i];
    __syncthreads();
    int r = threadIdx.x / 40, e = threadIdx.x % 40;
    const float* dr = dw + e * 64;
    const float* fr = fl + r * 64;
    float acc = 0.f;
    for (int i = 0; i < 64; ++i) acc += fr[i] * dr[i];
    h[(size_t)(row0 + r) * cE + e] += acc;
}

// ---------------- final LN + out projection ----------------
__global__ __launch_bounds__(256) void final_k(const float* __restrict__ h, const float* __restrict__ lnw,
                                               const float* __restrict__ ow, const float* __restrict__ ob,
                                               float* __restrict__ out) {
    int rid = blockIdx.x * 256 + threadIdx.x;
    const float* r = h + (size_t)rid * cE;
    float mu = 0;
    for (int k = 0; k < cE; ++k) mu += r[k];
    mu *= (1.f / cE);
    float va = 0;
    for (int k = 0; k < cE; ++k) { float d = r[k] - mu; va += d * d; }
    va *= (1.f / cE);
    float rs = rsqrtf(va + 1e-5f);
    float acc = ob[0];
    for (int k = 0; k < cE; ++k) acc += (r[k] - mu) * rs * lnw[k] * ow[k];
    out[rid] = acc;
}

extern "C" void kernel_launch(void* const* d_in, const int* in_sizes, int n_in,
                              void* d_out, int out_size, void* d_ws, size_t ws_size,
                              hipStream_t stream) {
    const float* x        = (const float*)d_in[0];
    const float* in_w     = (const float*)d_in[1];
    const float* in_b     = (const float*)d_in[2];
    const float* m_ln_w   = (const float*)d_in[3];
    const float* m_up_w   = (const float*)d_in[4];
    const float* m_conv_w = (const float*)d_in[5];
    const float* m_conv_b = (const float*)d_in[6];
    const float* m_q_w    = (const float*)d_in[7];
    const float* m_k_w    = (const float*)d_in[8];
    const float* m_v_w    = (const float*)d_in[9];
    const float* m_ig_w   = (const float*)d_in[10];
    const float* m_ig_b   = (const float*)d_in[11];
    const float* m_fg_w   = (const float*)d_in[12];
    const float* m_fg_b   = (const float*)d_in[13];
    const float* m_mhn_w  = (const float*)d_in[14];
    const float* m_skip   = (const float*)d_in[15];
    const float* m_down_w = (const float*)d_in[16];
    const float* s_ln1_w  = (const float*)d_in[17];
    const float* s_conv_w = (const float*)d_in[18];
    const float* s_conv_b = (const float*)d_in[19];
    const float* s_wi     = (const float*)d_in[20];
    const float* s_wf     = (const float*)d_in[21];
    const float* s_wz     = (const float*)d_in[22];
    const float* s_wo     = (const float*)d_in[23];
    const float* s_R      = (const float*)d_in[24];
    const float* s_bias   = (const float*)d_in[25];
    const float* s_mhn_w  = (const float*)d_in[26];
    const float* s_ln2_w  = (const float*)d_in[27];
    const float* s_ff_up  = (const float*)d_in[28];
    const float* s_ff_dn  = (const float*)d_in[29];
    const float* post_ln_w= (const float*)d_in[30];
    const float* out_w    = (const float*)d_in[31];
    const float* out_b    = (const float*)d_in[32];

    float* ws   = (float*)d_ws;
    float* h    = ws;                     // 1,310,720
    float* xmz  = h + 1310720;            // 8,388,608
    float* xc   = xmz + 8388608;          // 4,194,304
    float* qb   = xc + 4194304;           // 4,194,304
    float* kb   = qb + 4194304;           // 4,194,304
    float* vb   = kb + 4194304;           // 4,194,304
    float* ipb  = vb + 4194304;           //   262,144
    float* fpb  = ipb + 262144;           //   262,144
    float* hatt = fpb + 262144;           // 4,194,304   (~119 MB total)
    // slstm / ff aliases into the xmz region (dead at those points)
    float* lnbuf = xmz;                   // 1,310,720
    float* xcs   = xmz + 1310720;         // 1,310,720
    float* gall  = xmz + 2621440;         // 5,242,880 (+ scan overreads 8 steps into tail slack)
    float* ffbuf = xmz;                   // 2,097,152

    init_k<<<5120, 256, 0, stream>>>(x, in_w, in_b, h);

    auto mlstm = [&](int j) {
        ln_up_k<<<4096, 256, 0, stream>>>(h, m_ln_w + j * cE, m_up_w + (size_t)j * 256 * cE, xmz);
        conv_silu_k<128><<<16384, 256, 0, stream>>>(xmz, 256, m_conv_w + j * cI * cK, m_conv_b + j * cI, xc);
        qkv_k<<<16384, 256, 0, stream>>>(xc, xmz, m_q_w + j * 512, m_k_w + j * 512, m_v_w + j * 512, qb, kb, vb);
        gates_k<<<2048, 256, 0, stream>>>(qb, kb, vb, m_ig_w + j * cNH * 384, m_ig_b + j * cNH,
                                          m_fg_w + j * cNH * 384, m_fg_b + j * cNH, ipb, fpb);
        attn_k<<<1024, 64, 0, stream>>>(qb, kb, vb, ipb, fpb, hatt);
        mhn_y_k<<<1024, 256, 0, stream>>>(hatt, xc, xmz, m_mhn_w + j * cI, m_skip + j * cI);
        down_res_k<<<4096, 320, 0, stream>>>(hatt, m_down_w + j * cE * cI, h);
    };

    mlstm(0);

    ln_rows_k<<<128, 256, 0, stream>>>(h, s_ln1_w, lnbuf);
    conv_silu_k<40><<<5120, 256, 0, stream>>>(lnbuf, 40, s_conv_w, s_conv_b, xcs);
    sgates_k<<<20480, 256, 0, stream>>>(xcs, lnbuf, s_wi, s_wf, s_wz, s_wo, gall);
    scan_k<<<64, 1024, 0, stream>>>(gall, s_R, s_bias, s_mhn_w, h);

    ff1_k<<<8192, 256, 0, stream>>>(h, s_ln2_w, s_ff_up, ffbuf);
    ff2_k<<<4096, 320, 0, stream>>>(ffbuf, s_ff_dn, h);

    mlstm(1);
    mlstm(2);

    final_k<<<128, 256, 0, stream>>>(h, post_ln_w, out_w, out_b, (float*)d_out);
}

// Round 4
// 1321.826 us; speedup vs baseline: 1.1384x; 1.1384x over previous
//
#include <hip/hip_runtime.h>
#include <math.h>

constexpr int cB = 128, cS = 256, cF = 10, cE = 40, cNH = 8, cDH = 5;
constexpr int cI = 128, cMDH = 16, cK = 4;

// broadcast lane (group_base + l) to all 8 lanes of the group (groups of 8 within 32-lane halves)
#define BC8(v, l) __uint_as_float(__builtin_amdgcn_ds_swizzle(__float_as_uint(v), ((l) << 5) | 0x18))

// ---------------- h = x @ in_w.T + in_b + pos_encoding ----------------
__global__ __launch_bounds__(256) void init_k(const float* __restrict__ x, const float* __restrict__ w,
                                              const float* __restrict__ b, float* __restrict__ h) {
    int idx = blockIdx.x * 256 + threadIdx.x;     // B*S*E
    int e = idx % cE; int bs = idx / cE; int s = bs % cS;
    float acc = b[e];
    const float* xr = x + (size_t)bs * cF;
#pragma unroll
    for (int f = 0; f < cF; ++f) acc += xr[f] * w[e * cF + f];
    int i2 = e >> 1;
    float div = expf(-(float)(2 * i2) * (logf(10000.f) / 40.0f));
    float arg = (float)s * div;
    acc += (e & 1) ? cosf(arg) : sinf(arg);
    h[idx] = acc;
}

// ---------------- fused LayerNorm + up-projection (E=40 -> 256) ----------------
__global__ __launch_bounds__(256) void ln_up_k(const float* __restrict__ h, const float* __restrict__ lnw,
                                               const float* __restrict__ upw, float* __restrict__ xmz) {
    __shared__ float lnr[8][cE];
    int row0 = blockIdx.x * 8;
    int tid = threadIdx.x;
    if (tid < 8) {
        const float* r = h + (size_t)(row0 + tid) * cE;
        float mu = 0.f;
        for (int k = 0; k < cE; ++k) mu += r[k];
        mu *= (1.f / cE);
        float va = 0.f;
        for (int k = 0; k < cE; ++k) { float d = r[k] - mu; va += d * d; }
        va *= (1.f / cE);
        float rs = rsqrtf(va + 1e-5f);
        for (int k = 0; k < cE; ++k) lnr[tid][k] = (r[k] - mu) * rs * lnw[k];
    }
    __syncthreads();
    int o = tid;   // 0..255
    float acc[8] = {0, 0, 0, 0, 0, 0, 0, 0};
    for (int k = 0; k < cE; ++k) {
        float wv = upw[o * cE + k];
#pragma unroll
        for (int r = 0; r < 8; ++r) acc[r] += lnr[r][k] * wv;
    }
#pragma unroll
    for (int r = 0; r < 8; ++r) xmz[(size_t)(row0 + r) * 256 + o] = acc[r];
}

// ---------------- depthwise causal conv (K=4) + SiLU ----------------
template <int C>
__global__ __launch_bounds__(256) void conv_silu_k(const float* __restrict__ in, int instride,
                                                   const float* __restrict__ w, const float* __restrict__ bias,
                                                   float* __restrict__ out) {
    int idx = blockIdx.x * 256 + threadIdx.x;   // B*S*C
    int c = idx % C; int bs = idx / C; int s = bs % cS;
    float acc = bias[c];
#pragma unroll
    for (int j = 0; j < cK; ++j) {
        int sj = s - 3 + j;
        if (sj >= 0) acc += in[(size_t)(bs + j - 3) * instride + c] * w[c * cK + j];
    }
    float sg = 1.f / (1.f + __expf(-acc));
    out[idx] = acc * sg;
}

// ---------------- block-diagonal headwise q,k,v ----------------
__global__ __launch_bounds__(256) void qkv_k(const float* __restrict__ xc, const float* __restrict__ xmz,
                                             const float* __restrict__ qw, const float* __restrict__ kw,
                                             const float* __restrict__ vw,
                                             float* __restrict__ qb, float* __restrict__ kb, float* __restrict__ vb) {
    int idx = blockIdx.x * 256 + threadIdx.x;   // B*S*I
    int c = idx & 127; int bs = idx >> 7;
    int n = c >> 2, o = c & 3;
    const float* xcr = xc + (size_t)bs * cI + n * 4;
    const float* xmr = xmz + (size_t)bs * 256 + n * 4;
    const float* qwp = qw + n * 16 + o * 4;
    const float* kwp = kw + n * 16 + o * 4;
    const float* vwp = vw + n * 16 + o * 4;
    float aq = 0, ak = 0, av = 0;
#pragma unroll
    for (int i = 0; i < 4; ++i) { float a = xcr[i], m = xmr[i]; aq += a * qwp[i]; ak += a * kwp[i]; av += m * vwp[i]; }
    qb[idx] = aq; kb[idx] = ak; vb[idx] = av;
}

// ---------------- input/forget gate pre-activations ip, fp (B,NH,S) ----------------
__global__ __launch_bounds__(256) void gates_k(const float* __restrict__ qb, const float* __restrict__ kb,
                                               const float* __restrict__ vb, const float* __restrict__ igw,
                                               const float* __restrict__ igb, const float* __restrict__ fgw,
                                               const float* __restrict__ fgb,
                                               float* __restrict__ ipb, float* __restrict__ fpb) {
    __shared__ float g[16 * 388];   // padded stride (384%32==0 would be 16-way conflict)
    int row0 = blockIdx.x * 16;
    for (int i = threadIdx.x; i < 16 * 384; i += 256) {
        int r = i / 384, c = i % 384;
        size_t gr = (size_t)(row0 + r) * cI;
        float v;
        if (c < 128) v = qb[gr + c];
        else if (c < 256) v = kb[gr + c - 128];
        else v = vb[gr + c - 256];
        g[r * 388 + c] = v;
    }
    __syncthreads();
    int r = threadIdx.x >> 4; int ho = threadIdx.x & 15;
    int h = ho & 7; int wch = ho >> 3;
    const float* W = (wch ? fgw : igw) + h * 384;
    const float* gr2 = g + r * 388;
    float acc = 0.f;
    for (int c = 0; c < 384; ++c) acc += gr2[c] * W[c];
    acc += wch ? fgb[h] : igb[h];
    int grow = row0 + r; int b = grow >> 8; int s = grow & 255;
    float* dst = wch ? fpb : ipb;
    dst[(size_t)(b * cNH + h) * cS + s] = acc;
}

// ---------------- fused mLSTM attention: gate scans + causal qk*D*v ----------------
// 1 wave per (b,h); 4 rows/thread; K/V broadcast from LDS, amortized over 4 rows.
__global__ __launch_bounds__(64) void attn_k(const float* __restrict__ qg, const float* __restrict__ kg,
                                             const float* __restrict__ vg, const float* __restrict__ ipg,
                                             const float* __restrict__ fpg, float* __restrict__ hatt) {
    int bh = blockIdx.x; int b = bh >> 3, h = bh & 7;
    int lane = threadIdx.x;
    __shared__ float sA[cS], sMx[cS], sFc[cS];
    __shared__ float sKf[cS * cMDH], sVf[cS * cMDH];

    // --- Fc = cumsum(log_sigmoid(fp)); a[t]=ip[t]-Fc[t]; Mx = prefix-max(a) ---
    const float4 fp4 = ((const float4*)(fpg + (size_t)bh * cS))[lane];
    const float4 ip4 = ((const float4*)(ipg + (size_t)bh * cS))[lane];
    float fpa[4] = {fp4.x, fp4.y, fp4.z, fp4.w};
    float ipa[4] = {ip4.x, ip4.y, ip4.z, ip4.w};
    float p[4];
    {
        float run = 0.f;
#pragma unroll
        for (int i = 0; i < 4; ++i) {
            float xx = fpa[i];
            float lsg = fminf(xx, 0.f) - log1pf(expf(-fabsf(xx)));
            run += lsg; p[i] = run;
        }
    }
    float cum = p[3];
#pragma unroll
    for (int off = 1; off < 64; off <<= 1) { float t = __shfl_up(cum, off); if (lane >= off) cum += t; }
    float excl = cum - p[3];
    float aa[4];
#pragma unroll
    for (int i = 0; i < 4; ++i) {
        float fcv = excl + p[i];
        aa[i] = ipa[i] - fcv;
        sFc[lane * 4 + i] = fcv;
        sA[lane * 4 + i] = aa[i];
    }
    float mq[4]; mq[0] = aa[0];
#pragma unroll
    for (int i = 1; i < 4; ++i) mq[i] = fmaxf(mq[i - 1], aa[i]);
    float cm = mq[3];
#pragma unroll
    for (int off = 1; off < 64; off <<= 1) { float t = __shfl_up(cm, off); if (lane >= off) cm = fmaxf(cm, t); }
    float exm = __shfl_up(cm, 1);
    if (lane == 0) exm = -3.0e38f;
#pragma unroll
    for (int i = 0; i < 4; ++i) sMx[lane * 4 + i] = fmaxf(exm, mq[i]);

    // --- stage K,V to LDS; q to registers ---
    float qreg[4][16];
#pragma unroll
    for (int r = 0; r < 4; ++r) {
        int t = lane + 64 * r;
        const float4* kp = (const float4*)(kg + ((size_t)(b * cS) + t) * cI + h * cMDH);
        const float4* vp = (const float4*)(vg + ((size_t)(b * cS) + t) * cI + h * cMDH);
        float4* kd = (float4*)(sKf + t * cMDH);
        float4* vd = (float4*)(sVf + t * cMDH);
#pragma unroll
        for (int j = 0; j < 4; ++j) { kd[j] = kp[j]; vd[j] = vp[j]; }
        const float4* qp = (const float4*)(qg + ((size_t)(b * cS) + t) * cI + h * cMDH);
#pragma unroll
        for (int j = 0; j < 4; ++j) {
            float4 t4 = qp[j];
            qreg[r][4 * j] = t4.x; qreg[r][4 * j + 1] = t4.y; qreg[r][4 * j + 2] = t4.z; qreg[r][4 * j + 3] = t4.w;
        }
    }
    __syncthreads();

    float MxR[4], flr[4];
#pragma unroll
    for (int r = 0; r < 4; ++r) { int s = lane + 64 * r; MxR[r] = sMx[s]; flr[r] = expf(-(sFc[s] + sMx[s])); }
    float acc[4][16];
#pragma unroll
    for (int r = 0; r < 4; ++r)
#pragma unroll
        for (int d = 0; d < 16; ++d) acc[r][d] = 0.f;
    float sumC[4] = {0, 0, 0, 0};

    for (int t = 0; t < cS; ++t) {
        float at = sA[t];
        float kv[16], vv[16];
#pragma unroll
        for (int j = 0; j < 4; ++j) {
            float4 t4 = ((const float4*)(sKf + t * cMDH))[j];
            kv[4 * j] = t4.x; kv[4 * j + 1] = t4.y; kv[4 * j + 2] = t4.z; kv[4 * j + 3] = t4.w;
            float4 u4 = ((const float4*)(sVf + t * cMDH))[j];
            vv[4 * j] = u4.x; vv[4 * j + 1] = u4.y; vv[4 * j + 2] = u4.z; vv[4 * j + 3] = u4.w;
        }
#pragma unroll
        for (int r = 0; r < 4; ++r) {
            if (t <= 63 + 64 * r) {               // uniform: whole wave skips dead chunks
                if (t <= lane + 64 * r) {         // per-lane causal mask
                    float wgt = __expf(at - MxR[r]);   // a[t]-Mx[s] <= 0
                    float qk = 0.f;
#pragma unroll
                    for (int d = 0; d < 16; ++d) qk += qreg[r][d] * kv[d];
                    float ccf = qk * 0.25f * wgt;
                    sumC[r] += ccf;
#pragma unroll
                    for (int d = 0; d < 16; ++d) acc[r][d] += ccf * vv[d];
                }
            }
        }
    }
#pragma unroll
    for (int r = 0; r < 4; ++r) {
        int s = lane + 64 * r;
        float nrm = fmaxf(fabsf(sumC[r]), flr[r]) + 1e-6f;
        float inv = 1.f / nrm;
        float4* op = (float4*)(hatt + ((size_t)(b * cS) + s) * cI + h * cMDH);
#pragma unroll
        for (int j = 0; j < 4; ++j)
            op[j] = make_float4(acc[r][4 * j] * inv, acc[r][4 * j + 1] * inv,
                                acc[r][4 * j + 2] * inv, acc[r][4 * j + 3] * inv);
    }
}

// ---------------- multihead-norm + skip*x_c, gated by silu(z); in-place on hatt ----------------
__global__ __launch_bounds__(256) void mhn_y_k(float* __restrict__ hatt, const float* __restrict__ xc,
                                               const float* __restrict__ xmz, const float* __restrict__ mhnw,
                                               const float* __restrict__ skip) {
    int idx = blockIdx.x * 256 + threadIdx.x;   // B*S*NH
    int h = idx & 7; int row = idx >> 3;
    float* hp = hatt + (size_t)row * cI + h * cMDH;
    float xv[16];
#pragma unroll
    for (int d = 0; d < 16; ++d) xv[d] = hp[d];
    float mu = 0;
#pragma unroll
    for (int d = 0; d < 16; ++d) mu += xv[d];
    mu *= (1.f / 16);
    float va = 0;
#pragma unroll
    for (int d = 0; d < 16; ++d) { float dd = xv[d] - mu; va += dd * dd; }
    va *= (1.f / 16);
    float rs = rsqrtf(va + 1e-5f);
#pragma unroll
    for (int d = 0; d < 16; ++d) {
        int i = h * cMDH + d;
        float z = xmz[(size_t)row * 256 + 128 + i];
        float sg = 1.f / (1.f + __expf(-z));
        hp[d] = ((xv[d] - mu) * rs * mhnw[i] + skip[i] * xc[(size_t)row * cI + i]) * (z * sg);
    }
}

// ---------------- down-projection (128 -> 40) + residual into h ----------------
__global__ __launch_bounds__(320) void down_res_k(const float* __restrict__ y, const float* __restrict__ dw,
                                                  float* __restrict__ h) {
    __shared__ float yl[8 * 128];
    int row0 = blockIdx.x * 8;
    for (int i = threadIdx.x; i < 1024; i += 320) yl[i] = y[(size_t)row0 * cI + i];
    __syncthreads();
    int r = threadIdx.x / 40, e = threadIdx.x % 40;
    const float* dr = dw + e * cI;
    const float* yr = yl + r * cI;
    float acc = 0.f;
    for (int i = 0; i < cI; ++i) acc += yr[i] * dr[i];
    h[(size_t)(row0 + r) * cE + e] += acc;
}

// ---------------- plain row LayerNorm (E=40) ----------------
__global__ __launch_bounds__(256) void ln_rows_k(const float* __restrict__ h, const float* __restrict__ w,
                                                 float* __restrict__ out) {
    int rid = blockIdx.x * 256 + threadIdx.x;
    const float* r = h + (size_t)rid * cE;
    float mu = 0;
    for (int k = 0; k < cE; ++k) mu += r[k];
    mu *= (1.f / cE);
    float va = 0;
    for (int k = 0; k < cE; ++k) { float d = r[k] - mu; va += d * d; }
    va *= (1.f / cE);
    float rs = rsqrtf(va + 1e-5f);
    float* o = out + (size_t)rid * cE;
    for (int k = 0; k < cE; ++k) o[k] = (r[k] - mu) * rs * w[k];
}

// ---------------- sLSTM gate pre-activations; gall layout (S, B*NH, E=5, G=4) ----------------
// g fastest: scan lane e reads one float4 = (i,f,z,o); 40 active lanes/wave read
// 8 chains * 80B contiguous per step.
__global__ __launch_bounds__(256) void sgates_k(const float* __restrict__ xcs, const float* __restrict__ ln1,
                                                const float* __restrict__ wi, const float* __restrict__ wf,
                                                const float* __restrict__ wz, const float* __restrict__ wo,
                                                float* __restrict__ gall) {
    int idx = blockIdx.x * 256 + threadIdx.x;   // S*1024*5*4
    int g = idx & 3; int r1 = idx >> 2;
    int e = r1 % 5; int r2 = r1 / 5;
    int bh = r2 & 1023; int s = r2 >> 10;
    int b = bh >> 3, h = bh & 7;
    const float* in = (g < 2) ? xcs : ln1;
    const float* w = (g == 0) ? wi : (g == 1) ? wf : (g == 2) ? wz : wo;
    const float* ir = in + ((size_t)(b * cS) + s) * cE + h * cDH;
    const float* wp = w + h * 25 + e * 5;
    float acc = 0.f;
#pragma unroll
    for (int i = 0; i < 5; ++i) acc += ir[i] * wp[i];
    gall[idx] = acc;
}

// ---------------- sLSTM sequential scan: 8 chains per wave (8-lane groups) ----------------
// Full-lane waves kill the 5/64-lane instruction waste of R1/R2. 128 waves spread
// 1/SIMD over 128 CUs. h-broadcast via static ds_swizzle within 8-lane groups.
// Lanes e>=5 clone e=4 (valid weights, no divergence); only e<5 writes results.
// gall register-ring prefetch depth 8; norm output stashed in LDS, flushed once.
__global__ __launch_bounds__(64) void scan_k(const float* __restrict__ gall, const float* __restrict__ R,
                                             const float* __restrict__ bias, const float* __restrict__ mhnw,
                                             float* __restrict__ hbuf) {
    int lane = threadIdx.x;
    int grp = lane >> 3;                 // chain within wave, 0..7
    int e = lane & 7;                    // 0..4 active, 5..7 clone e=4
    int ee = e < 5 ? e : 4;
    int bh = blockIdx.x * 8 + grp;       // 128 blocks * 8 = 1024 chains
    int h = bh & 7;

    __shared__ float sOut[8][1285];      // stride 1285 (== 5 mod 32): groups hit different banks

    float Rr[4][5];                      // R[h][g][d][ee]
#pragma unroll
    for (int g = 0; g < 4; ++g)
#pragma unroll
        for (int d = 0; d < 5; ++d) Rr[g][d] = R[h * 100 + g * 25 + d * 5 + ee];
    float bg[4];
#pragma unroll
    for (int g = 0; g < 4; ++g) bg[g] = bias[h * 20 + g * 5 + ee];
    float wmh = mhnw[h * 5 + ee];

    // float4 index (t*1024 + bh)*5 + ee ; per-step stride 5120 float4s
    const float4* gp = (const float4*)gall + ((size_t)bh * 5 + ee);

    float4 rg[8];
#pragma unroll
    for (int j = 0; j < 8; ++j) rg[j] = gp[(size_t)j * 5120];

    float cstate = 0.f, nstate = 0.f, mstate = 0.f;
    float hs0 = 0.f, hs1 = 0.f, hs2 = 0.f, hs3 = 0.f, hs4 = 0.f;

    for (int t = 0; t < cS; t += 8) {
#pragma unroll
        for (int j = 0; j < 8; ++j) {
            float4 g4 = rg[j];
            rg[j] = gp[(size_t)(t + j + 8) * 5120];   // overread past t=255 lands in ws slack

            float ir = g4.x + bg[0], fr = g4.y + bg[1], zr = g4.z + bg[2], orr = g4.w + bg[3];
            ir = fmaf(hs0, Rr[0][0], ir); fr = fmaf(hs0, Rr[1][0], fr);
            zr = fmaf(hs0, Rr[2][0], zr); orr = fmaf(hs0, Rr[3][0], orr);
            ir = fmaf(hs1, Rr[0][1], ir); fr = fmaf(hs1, Rr[1][1], fr);
            zr = fmaf(hs1, Rr[2][1], zr); orr = fmaf(hs1, Rr[3][1], orr);
            ir = fmaf(hs2, Rr[0][2], ir); fr = fmaf(hs2, Rr[1][2], fr);
            zr = fmaf(hs2, Rr[2][2], zr); orr = fmaf(hs2, Rr[3][2], orr);
            ir = fmaf(hs3, Rr[0][3], ir); fr = fmaf(hs3, Rr[1][3], fr);
            zr = fmaf(hs3, Rr[2][3], zr); orr = fmaf(hs3, Rr[3][3], orr);
            ir = fmaf(hs4, Rr[0][4], ir); fr = fmaf(hs4, Rr[1][4], fr);
            zr = fmaf(hs4, Rr[2][4], zr); orr = fmaf(hs4, Rr[3][4], orr);

            float lsg = fminf(fr, 0.f) - __logf(1.f + __expf(-fabsf(fr)));
            float lfm = mstate + lsg;
            float mn = fmaxf(ir, lfm);
            float ig = __expf(ir - mn), fg = __expf(lfm - mn);
            float th = 1.f - 2.f * __builtin_amdgcn_rcpf(__expf(2.f * zr) + 1.f);
            float cn = fg * cstate + ig * th;
            float nn = fg * nstate + ig;
            float sg = __builtin_amdgcn_rcpf(1.f + __expf(-orr));
            float hn = sg * cn * __builtin_amdgcn_rcpf(nn);
            cstate = cn; nstate = nn; mstate = mn;

            hs0 = BC8(hn, 0); hs1 = BC8(hn, 1); hs2 = BC8(hn, 2);
            hs3 = BC8(hn, 3); hs4 = BC8(hn, 4);
            float mu = ((hs0 + hs1) + (hs2 + hs3) + hs4) * 0.2f;
            float d0 = hs0 - mu, d1 = hs1 - mu, d2 = hs2 - mu, d3 = hs3 - mu, d4 = hs4 - mu;
            float va = (d0 * d0 + d1 * d1 + d2 * d2 + d3 * d3 + d4 * d4) * 0.2f;
            float rs = __builtin_amdgcn_rsqf(va + 1e-5f);
            if (e < 5) sOut[grp][(t + j) * 5 + e] = (hn - mu) * rs * wmh;
        }
    }
    __syncthreads();

    // flush with residual add: h[b, t, h*5+e] += sOut
    for (int i = lane; i < 8 * 1280; i += 64) {
        int c = i >> 10; c = i / 1280;
        int r = i - c * 1280;
        int tt = r / 5, e2 = r - tt * 5;
        int bh2 = blockIdx.x * 8 + c;
        int b2 = bh2 >> 3, h2 = bh2 & 7;
        float* hp = hbuf + ((size_t)b2 * cS + tt) * cE + h2 * cDH + e2;
        *hp += sOut[c][r];
    }
}

// ---------------- FFN: fused LN + up-proj + exact GELU gate ----------------
__global__ __launch_bounds__(256) void ff1_k(const float* __restrict__ h, const float* __restrict__ lnw,
                                             const float* __restrict__ upw, float* __restrict__ ff) {
    __shared__ float lnr[4][cE];
    int row0 = blockIdx.x * 4;
    int tid = threadIdx.x;
    if (tid < 4) {
        const float* r = h + (size_t)(row0 + tid) * cE;
        float mu = 0;
        for (int k = 0; k < cE; ++k) mu += r[k];
        mu *= (1.f / cE);
        float va = 0;
        for (int k = 0; k < cE; ++k) { float d = r[k] - mu; va += d * d; }
        va *= (1.f / cE);
        float rs = rsqrtf(va + 1e-5f);
        for (int k = 0; k < cE; ++k) lnr[tid][k] = (r[k] - mu) * rs * lnw[k];
    }
    __syncthreads();
    int r = tid >> 6, f = tid & 63;
    float a = 0, u = 0;
    for (int k = 0; k < cE; ++k) {
        float xv = lnr[r][k];
        a += xv * upw[f * cE + k];
        u += xv * upw[(64 + f) * cE + k];
    }
    float g = 0.5f * a * (1.f + erff(a * 0.70710678118f));
    ff[(size_t)(row0 + r) * 64 + f] = g * u;
}

__global__ __launch_bounds__(320) void ff2_k(const float* __restrict__ ff, const float* __restrict__ dw,
                                             float* __restrict__ h) {
    __shared__ float fl[8 * 64];
    int row0 = blockIdx.x * 8;
    for (int i = threadIdx.x; i < 512; i += 320) fl[i] = ff[(size_t)row0 * 64 + i];
    __syncthreads();
    int r = threadIdx.x / 40, e = threadIdx.x % 40;
    const float* dr = dw + e * 64;
    const float* fr = fl + r * 64;
    float acc = 0.f;
    for (int i = 0; i < 64; ++i) acc += fr[i] * dr[i];
    h[(size_t)(row0 + r) * cE + e] += acc;
}

// ---------------- final LN + out projection ----------------
__global__ __launch_bounds__(256) void final_k(const float* __restrict__ h, const float* __restrict__ lnw,
                                               const float* __restrict__ ow, const float* __restrict__ ob,
                                               float* __restrict__ out) {
    int rid = blockIdx.x * 256 + threadIdx.x;
    const float* r = h + (size_t)rid * cE;
    float mu = 0;
    for (int k = 0; k < cE; ++k) mu += r[k];
    mu *= (1.f / cE);
    float va = 0;
    for (int k = 0; k < cE; ++k) { float d = r[k] - mu; va += d * d; }
    va *= (1.f / cE);
    float rs = rsqrtf(va + 1e-5f);
    float acc = ob[0];
    for (int k = 0; k < cE; ++k) acc += (r[k] - mu) * rs * lnw[k] * ow[k];
    out[rid] = acc;
}

extern "C" void kernel_launch(void* const* d_in, const int* in_sizes, int n_in,
                              void* d_out, int out_size, void* d_ws, size_t ws_size,
                              hipStream_t stream) {
    const float* x        = (const float*)d_in[0];
    const float* in_w     = (const float*)d_in[1];
    const float* in_b     = (const float*)d_in[2];
    const float* m_ln_w   = (const float*)d_in[3];
    const float* m_up_w   = (const float*)d_in[4];
    const float* m_conv_w = (const float*)d_in[5];
    const float* m_conv_b = (const float*)d_in[6];
    const float* m_q_w    = (const float*)d_in[7];
    const float* m_k_w    = (const float*)d_in[8];
    const float* m_v_w    = (const float*)d_in[9];
    const float* m_ig_w   = (const float*)d_in[10];
    const float* m_ig_b   = (const float*)d_in[11];
    const float* m_fg_w   = (const float*)d_in[12];
    const float* m_fg_b   = (const float*)d_in[13];
    const float* m_mhn_w  = (const float*)d_in[14];
    const float* m_skip   = (const float*)d_in[15];
    const float* m_down_w = (const float*)d_in[16];
    const float* s_ln1_w  = (const float*)d_in[17];
    const float* s_conv_w = (const float*)d_in[18];
    const float* s_conv_b = (const float*)d_in[19];
    const float* s_wi     = (const float*)d_in[20];
    const float* s_wf     = (const float*)d_in[21];
    const float* s_wz     = (const float*)d_in[22];
    const float* s_wo     = (const float*)d_in[23];
    const float* s_R      = (const float*)d_in[24];
    const float* s_bias   = (const float*)d_in[25];
    const float* s_mhn_w  = (const float*)d_in[26];
    const float* s_ln2_w  = (const float*)d_in[27];
    const float* s_ff_up  = (const float*)d_in[28];
    const float* s_ff_dn  = (const float*)d_in[29];
    const float* post_ln_w= (const float*)d_in[30];
    const float* out_w    = (const float*)d_in[31];
    const float* out_b    = (const float*)d_in[32];

    float* ws   = (float*)d_ws;
    float* h    = ws;                     // 1,310,720
    float* xmz  = h + 1310720;            // 8,388,608
    float* xc   = xmz + 8388608;          // 4,194,304
    float* qb   = xc + 4194304;           // 4,194,304
    float* kb   = qb + 4194304;           // 4,194,304
    float* vb   = kb + 4194304;           // 4,194,304
    float* ipb  = vb + 4194304;           //   262,144
    float* fpb  = ipb + 262144;           //   262,144
    float* hatt = fpb + 262144;           // 4,194,304   (~119 MB total)
    // slstm / ff aliases into the xmz region (dead at those points)
    float* lnbuf = xmz;                   // 1,310,720
    float* xcs   = xmz + 1310720;         // 1,310,720
    float* gall  = xmz + 2621440;         // 5,242,880 (+ scan overreads 8 steps into tail slack)
    float* ffbuf = xmz;                   // 2,097,152

    init_k<<<5120, 256, 0, stream>>>(x, in_w, in_b, h);

    auto mlstm = [&](int j) {
        ln_up_k<<<4096, 256, 0, stream>>>(h, m_ln_w + j * cE, m_up_w + (size_t)j * 256 * cE, xmz);
        conv_silu_k<128><<<16384, 256, 0, stream>>>(xmz, 256, m_conv_w + j * cI * cK, m_conv_b + j * cI, xc);
        qkv_k<<<16384, 256, 0, stream>>>(xc, xmz, m_q_w + j * 512, m_k_w + j * 512, m_v_w + j * 512, qb, kb, vb);
        gates_k<<<2048, 256, 0, stream>>>(qb, kb, vb, m_ig_w + j * cNH * 384, m_ig_b + j * cNH,
                                          m_fg_w + j * cNH * 384, m_fg_b + j * cNH, ipb, fpb);
        attn_k<<<1024, 64, 0, stream>>>(qb, kb, vb, ipb, fpb, hatt);
        mhn_y_k<<<1024, 256, 0, stream>>>(hatt, xc, xmz, m_mhn_w + j * cI, m_skip + j * cI);
        down_res_k<<<4096, 320, 0, stream>>>(hatt, m_down_w + j * cE * cI, h);
    };

    mlstm(0);

    ln_rows_k<<<128, 256, 0, stream>>>(h, s_ln1_w, lnbuf);
    conv_silu_k<40><<<5120, 256, 0, stream>>>(lnbuf, 40, s_conv_w, s_conv_b, xcs);
    sgates_k<<<20480, 256, 0, stream>>>(xcs, lnbuf, s_wi, s_wf, s_wz, s_wo, gall);
    scan_k<<<128, 64, 0, stream>>>(gall, s_R, s_bias, s_mhn_w, h);

    ff1_k<<<8192, 256, 0, stream>>>(h, s_ln2_w, s_ff_up, ffbuf);
    ff2_k<<<4096, 320, 0, stream>>>(ffbuf, s_ff_dn, h);

    mlstm(1);
    mlstm(2);

    final_k<<<128, 256, 0, stream>>>(h, post_ln_w, out_w, out_b, (float*)d_out);
}